// Round 6
// baseline (796.585 us; speedup 1.0000x reference)
//
#include <hip/hip_runtime.h>
#include <hip/hip_bf16.h>

#define Lv 1024
#define Vv 96
#define Ev 64
#define Hv 256
#define NB 4      // batch rows per WG (primary path)
#define ROWS 16   // batch rows per WG (fallback path)
#define HOFF (256 * 1024 * 96)
#define EPAD 72
#define HBP 1024  // ushorts per h buffer, primary (4 x 256)
#define HB 4096   // ushorts per h buffer, fallback (16 x 256)

typedef __attribute__((ext_vector_type(8))) short bf16x8;
typedef __attribute__((ext_vector_type(4))) float f32x4;
typedef __attribute__((ext_vector_type(2))) unsigned int u32x2;

__device__ __forceinline__ unsigned short f2b(float f) {
  unsigned u = __builtin_bit_cast(unsigned, f);
  return (unsigned short)((u + 0x7fffu + ((u >> 16) & 1u)) >> 16);  // RNE
}
__device__ __forceinline__ unsigned cvtpk_bf16(float lo, float hi) {
  unsigned r;
  asm("v_cvt_pk_bf16_f32 %0, %1, %2" : "=v"(r) : "v"(lo), "v"(hi));
  return r;
}
__device__ __forceinline__ float fast_tanh(float x) {
  float e = __builtin_amdgcn_exp2f(x * 2.885390081777927f);  // exp(2x)
  return 1.0f - 2.0f * __builtin_amdgcn_rcpf(e + 1.0f);
}
// lgkm-only barrier: LDS ordered, global stores keep draining across steps.
__device__ __forceinline__ void step_barrier() {
  asm volatile("s_waitcnt lgkmcnt(0)\n\ts_barrier" ::: "memory");
  __builtin_amdgcn_sched_barrier(0);
}

__global__ void detect_i64(const int* __restrict__ x, int* __restrict__ flag) {
  if (threadIdx.x == 0 && blockIdx.x == 0) {
    int ok = 1;
    for (int i = 0; i < 64; ++i) ok &= (x[2 * i + 1] == 0);
    *flag = ok;
  }
}

// ============================ primary loop =============================
// Transposed recurrence, 64 WGs x 4 batch cols, 8 waves. Wave w owns hidden
// rows [32w,32w+32). Lanes lm>=NB read DUPLICATE addresses (lm&3) so the LDS
// broadcast path dedups bank work; their MFMA cols are garbage and masked off
// at write/export. Logits deferred to full-chip GEMM over hs[t][b][h].
__global__ __launch_bounds__(512, 2) void rnn4t(
    const int* __restrict__ x, const float* __restrict__ h0,
    const float* __restrict__ emb, const float* __restrict__ W_ih,
    const float* __restrict__ b_ih, float* __restrict__ out,
    unsigned short* __restrict__ hs, const int* __restrict__ flagp) {
  const int tid = threadIdx.x;
  const int w = tid >> 6, ln = tid & 63, lm = ln & 15, g = ln >> 4;
  const int lmb = lm & (NB - 1);  // dedup batch col
  const int r0 = blockIdx.x * NB;

  __shared__ __attribute__((aligned(16))) unsigned short s_h[2 * HBP];
  __shared__ __attribute__((aligned(16))) unsigned short s_emb[Vv * EPAD];
  __shared__ unsigned char s_x[Lv * NB];

  const int flag = *flagp;  // 1 => x is int64

  for (int idx = tid; idx < Vv * Ev; idx += 512)
    s_emb[(idx >> 6) * EPAD + (idx & 63)] = f2b(emb[idx]);
  for (int idx = tid; idx < NB * Hv; idx += 512) {  // h_{-1} -> buf1
    int b_ = idx >> 8, hd = idx & 255;
    s_h[HBP + b_ * 256 + ((((hd >> 3) ^ b_) << 3) | (hd & 7))] =
        f2b(h0[(r0 + b_) * Hv + hd]);
  }
  for (int idx = tid; idx < NB * Lv; idx += 512) {  // x, transposed u8
    int t = idx >> 2, row = idx & (NB - 1);
    long long src = (long long)(r0 + row) * Lv + t;
    int v = flag ? x[2 * src] : x[src];
    s_x[t * NB + row] = (unsigned char)v;
  }

  // ---- register-resident weights (A-frags: row=lm, k=8g+i) ----
  bf16x8 wh[2][8], wx[2][2];
  f32x4 bihv[2];
#pragma unroll
  for (int nt = 0; nt < 2; ++nt) {
    const int n = 32 * w + 16 * nt + lm;  // output hidden row
#pragma unroll
    for (int kf = 0; kf < 8; ++kf)
#pragma unroll
      for (int i = 0; i < 8; ++i)
        wh[nt][kf][i] = (short)f2b(W_ih[(Ev + 32 * kf + 8 * g + i) * Hv + n]);
#pragma unroll
    for (int kf = 0; kf < 2; ++kf)
#pragma unroll
      for (int i = 0; i < 8; ++i)
        wx[nt][kf][i] = (short)f2b(W_ih[(32 * kf + 8 * g + i) * Hv + n]);
    bihv[nt] = *(const f32x4*)&b_ih[32 * w + 16 * nt + 4 * g];
  }

  // ---- loop-invariant addresses (deduped for lm >= NB) ----
  const unsigned short* ra[8];  // B-frag reads: batch col lmb, k = 32kf+8g+i
#pragma unroll
  for (int kf = 0; kf < 8; ++kf)
    ra[kf] = &s_h[lmb * 256 + (((4 * kf + g) ^ lmb) << 3)];
  unsigned short* wa[2];  // b64 writes (lm<NB): hidden 32w+16nt+4g, batch lm
#pragma unroll
  for (int nt = 0; nt < 2; ++nt)
    wa[nt] = &s_h[lmb * 256 + (((4 * w + 2 * nt + (g >> 1)) ^ lmb) << 3) +
                  ((g & 1) << 2)];
  unsigned short* hp = hs + (size_t)(r0 + lmb) * 256 + 32 * w + 4 * g;  // t=0

  __syncthreads();

  bf16x8 ef0, ef1;  // emb B-frags: col=batch lmb, k=8g+i / 32+8g+i
  int xi_n;
  {
    int xi0 = s_x[lmb];
    const unsigned short* ep = &s_emb[xi0 * EPAD + 8 * g];
    ef0 = *(const bf16x8*)ep;
    ef1 = *(const bf16x8*)(ep + 32);
    xi_n = s_x[NB + lmb];  // t=1
  }

#define STEP(TT, RB, WB, LAST)                                                    \
  do {                                                                            \
    bf16x8 af[8];                                                                 \
    _Pragma("unroll") for (int kf = 0; kf < 8; ++kf)                              \
        af[kf] = *(const bf16x8*)(ra[kf] + (RB));                                 \
    /* 4 depth-2 chains per nt */                                                 \
    f32x4 c00 = bihv[0], c01 = {0, 0, 0, 0}, c02 = {0, 0, 0, 0}, c03 = {0, 0, 0, 0}; \
    f32x4 c10 = bihv[1], c11 = {0, 0, 0, 0}, c12 = {0, 0, 0, 0}, c13 = {0, 0, 0, 0}; \
    c00 = __builtin_amdgcn_mfma_f32_16x16x32_bf16(wh[0][0], af[0], c00, 0, 0, 0); \
    c10 = __builtin_amdgcn_mfma_f32_16x16x32_bf16(wh[1][0], af[0], c10, 0, 0, 0); \
    c01 = __builtin_amdgcn_mfma_f32_16x16x32_bf16(wh[0][2], af[2], c01, 0, 0, 0); \
    c11 = __builtin_amdgcn_mfma_f32_16x16x32_bf16(wh[1][2], af[2], c11, 0, 0, 0); \
    c02 = __builtin_amdgcn_mfma_f32_16x16x32_bf16(wh[0][4], af[4], c02, 0, 0, 0); \
    c12 = __builtin_amdgcn_mfma_f32_16x16x32_bf16(wh[1][4], af[4], c12, 0, 0, 0); \
    c03 = __builtin_amdgcn_mfma_f32_16x16x32_bf16(wh[0][6], af[6], c03, 0, 0, 0); \
    c13 = __builtin_amdgcn_mfma_f32_16x16x32_bf16(wh[1][6], af[6], c13, 0, 0, 0); \
    c00 = __builtin_amdgcn_mfma_f32_16x16x32_bf16(wh[0][1], af[1], c00, 0, 0, 0); \
    c10 = __builtin_amdgcn_mfma_f32_16x16x32_bf16(wh[1][1], af[1], c10, 0, 0, 0); \
    c01 = __builtin_amdgcn_mfma_f32_16x16x32_bf16(wh[0][3], af[3], c01, 0, 0, 0); \
    c11 = __builtin_amdgcn_mfma_f32_16x16x32_bf16(wh[1][3], af[3], c11, 0, 0, 0); \
    c02 = __builtin_amdgcn_mfma_f32_16x16x32_bf16(wh[0][5], af[5], c02, 0, 0, 0); \
    c12 = __builtin_amdgcn_mfma_f32_16x16x32_bf16(wh[1][5], af[5], c12, 0, 0, 0); \
    c03 = __builtin_amdgcn_mfma_f32_16x16x32_bf16(wh[0][7], af[7], c03, 0, 0, 0); \
    c13 = __builtin_amdgcn_mfma_f32_16x16x32_bf16(wh[1][7], af[7], c13, 0, 0, 0); \
    c00 = __builtin_amdgcn_mfma_f32_16x16x32_bf16(wx[0][0], ef0, c00, 0, 0, 0);   \
    c10 = __builtin_amdgcn_mfma_f32_16x16x32_bf16(wx[1][0], ef0, c10, 0, 0, 0);   \
    c02 = __builtin_amdgcn_mfma_f32_16x16x32_bf16(wx[0][1], ef1, c02, 0, 0, 0);   \
    c12 = __builtin_amdgcn_mfma_f32_16x16x32_bf16(wx[1][1], ef1, c12, 0, 0, 0);   \
    { /* prefetch ef for TT+1, xi for TT+2 */                                     \
      const unsigned short* ep = &s_emb[xi_n * EPAD + 8 * g];                     \
      ef0 = *(const bf16x8*)ep;                                                   \
      ef1 = *(const bf16x8*)(ep + 32);                                            \
      int tn = ((TT) + 2 < Lv) ? (TT) + 2 : (Lv - 1);                             \
      xi_n = s_x[tn * NB + lmb];                                                  \
    }                                                                             \
    f32x4 s0, s1;                                                                 \
    _Pragma("unroll") for (int rr = 0; rr < 4; ++rr) {                            \
      s0[rr] = (c00[rr] + c01[rr]) + (c02[rr] + c03[rr]);                         \
      s1[rr] = (c10[rr] + c11[rr]) + (c12[rr] + c13[rr]);                         \
    }                                                                             \
    float h0v = fast_tanh(s0[0]), h1v = fast_tanh(s0[1]);                         \
    float h2v = fast_tanh(s0[2]), h3v = fast_tanh(s0[3]);                         \
    float h4v = fast_tanh(s1[0]), h5v = fast_tanh(s1[1]);                         \
    float h6v = fast_tanh(s1[2]), h7v = fast_tanh(s1[3]);                         \
    u32x2 p0, p1;                                                                 \
    p0[0] = cvtpk_bf16(h0v, h1v);                                                 \
    p0[1] = cvtpk_bf16(h2v, h3v);                                                 \
    p1[0] = cvtpk_bf16(h4v, h5v);                                                 \
    p1[1] = cvtpk_bf16(h6v, h7v);                                                 \
    if (lm < NB) {                                                                \
      *(u32x2*)(wa[0] + (WB)) = p0;                                               \
      *(u32x2*)(wa[1] + (WB)) = p1;                                               \
      *(u32x2*)hp = p0;        /* hs[TT], nt=0 */                                 \
      *(u32x2*)(hp + 16) = p1; /* hs[TT], nt=1 */                                 \
      if (LAST) {                                                                 \
        float* fo = out + HOFF + (size_t)(r0 + lm) * Hv + 32 * w + 4 * g;         \
        *(f32x4*)fo = (f32x4){h0v, h1v, h2v, h3v};                                \
        *(f32x4*)(fo + 16) = (f32x4){h4v, h5v, h6v, h7v};                         \
      }                                                                           \
    }                                                                             \
    hp += 256 * 256;                                                              \
    step_barrier();                                                               \
  } while (0)

  STEP(0, HBP, 0, 0);  // h_{-1}(buf1) -> h_0(buf0), export hs[0]
  for (int t = 1; t < Lv - 1; t += 2) {
    STEP(t, 0, HBP, 0);
    STEP(t + 1, HBP, 0, 0);
  }
  STEP(Lv - 1, 0, HBP, 1);  // h_1023, export hs[1023], final hidden fp32
#undef STEP
}

// Deferred logits: out[b][t][v] = hs[t][b][:]@W_ho + b_ho, full chip.
__global__ __launch_bounds__(512, 2) void logits_gemm(
    const unsigned short* __restrict__ hs, const float* __restrict__ W_ho,
    const float* __restrict__ b_ho, float* __restrict__ out) {
  const int tid = threadIdx.x;
  const int w = tid >> 6, ln = tid & 63, lm = ln & 15, g = ln >> 4;
  const int tg = blockIdx.x >> 2, bg = blockIdx.x & 3;

  // W_ho as B-frags: [vt 0..5][kf 0..7][lane][8 elems] bf16
  __shared__ __attribute__((aligned(16))) unsigned short s_who[3072 * 8];
  for (int f = tid; f < 3072; f += 512) {
    int vt = f >> 9, kf = (f >> 6) & 7, lane = f & 63;
    int k0 = 32 * kf + 8 * (lane >> 4), v = 16 * vt + (lane & 15);
    bf16x8 fr;
#pragma unroll
    for (int i = 0; i < 8; ++i) fr[i] = (short)f2b(W_ho[(k0 + i) * Vv + v]);
    *(bf16x8*)&s_who[f * 8] = fr;
  }
  __syncthreads();

  const int bt = w & 3, vg = w >> 2;
  const int b0 = bg * 64 + bt * 16;
  const int j0 = vg * 3;
  float bb[3];
#pragma unroll
  for (int jj = 0; jj < 3; ++jj) bb[jj] = b_ho[16 * (j0 + jj) + lm];

#pragma unroll
  for (int tt = 0; tt < 4; ++tt) {
    const int t = tg * 4 + tt;
    const unsigned short* hpb =
        hs + (size_t)t * (256 * 256) + (b0 + lm) * 256 + 8 * g;
    f32x4 acc[3];
#pragma unroll
    for (int jj = 0; jj < 3; ++jj)
      acc[jj] = (f32x4){bb[jj], bb[jj], bb[jj], bb[jj]};
#pragma unroll
    for (int kf = 0; kf < 8; ++kf) {
      bf16x8 af = *(const bf16x8*)(hpb + 32 * kf);
#pragma unroll
      for (int jj = 0; jj < 3; ++jj) {
        bf16x8 bw = *(const bf16x8*)&s_who[(((j0 + jj) * 8 + kf) * 64 + ln) * 8];
        acc[jj] =
            __builtin_amdgcn_mfma_f32_16x16x32_bf16(af, bw, acc[jj], 0, 0, 0);
      }
    }
#pragma unroll
    for (int jj = 0; jj < 3; ++jj)
#pragma unroll
      for (int rr = 0; rr < 4; ++rr)
        out[(size_t)(b0 + 4 * g + rr) * (Lv * Vv) + (size_t)t * Vv +
            16 * (j0 + jj) + lm] = acc[jj][rr];
  }
}

// ===================== fallback (R2 kernel, ws too small) =====================
__global__ __launch_bounds__(512, 2) void rnn8(
    const int* __restrict__ x, const float* __restrict__ h0,
    const float* __restrict__ emb, const float* __restrict__ W_ih,
    const float* __restrict__ b_ih, const float* __restrict__ W_ho,
    const float* __restrict__ b_ho, float* __restrict__ out,
    const int* __restrict__ flagp) {
  const int tid = threadIdx.x;
  const int w = tid >> 6, ln = tid & 63, lm = ln & 15, g = ln >> 4;
  const int r0 = blockIdx.x * ROWS;

  __shared__ __attribute__((aligned(16))) unsigned short s_emb[Vv * EPAD];
  __shared__ __attribute__((aligned(16))) unsigned short s_h[2 * HB];
  __shared__ unsigned char s_x[Lv * ROWS];

  const int flag = *flagp;

  for (int idx = tid; idx < Vv * Ev; idx += 512)
    s_emb[(idx >> 6) * EPAD + (idx & 63)] = f2b(emb[idx]);
  for (int idx = tid; idx < ROWS * Hv; idx += 512) {
    int m = idx >> 8, nn = idx & 255;
    s_h[HB + (m << 8) + ((((nn >> 3) ^ (m & 7)) << 3) | (nn & 7))] =
        f2b(h0[(r0 + m) * Hv + nn]);
  }
  for (int idx = tid; idx < ROWS * Lv; idx += 512) {
    int row = idx >> 10, t = idx & 1023;
    long long src = (long long)(r0 + row) * Lv + t;
    int v = flag ? x[2 * src] : x[src];
    s_x[t * ROWS + row] = (unsigned char)v;
  }

  bf16x8 wh[2][8], wx[2][2], who[8];
  float bih[2], bhov = 0.0f;
#pragma unroll
  for (int nt = 0; nt < 2; ++nt) {
    const int n = 32 * w + 16 * nt + lm;
    bih[nt] = b_ih[n];
#pragma unroll
    for (int kf = 0; kf < 8; ++kf)
#pragma unroll
      for (int i = 0; i < 8; ++i)
        wh[nt][kf][i] = (short)f2b(W_ih[(Ev + 32 * kf + 8 * g + i) * Hv + n]);
#pragma unroll
    for (int kf = 0; kf < 2; ++kf)
#pragma unroll
      for (int i = 0; i < 8; ++i)
        wx[nt][kf][i] = (short)f2b(W_ih[(32 * kf + 8 * g + i) * Hv + n]);
  }
  if (w < 6) {
    const int n = 16 * w + lm;
    bhov = b_ho[n];
#pragma unroll
    for (int kf = 0; kf < 8; ++kf)
#pragma unroll
      for (int i = 0; i < 8; ++i)
        who[kf][i] = (short)f2b(W_ho[(32 * kf + 8 * g + i) * Vv + n]);
  }

  const unsigned short* ra[8];
#pragma unroll
  for (int kf = 0; kf < 8; ++kf)
    ra[kf] = &s_h[(lm << 8) + (((4 * kf + g) ^ (lm & 7)) << 3)];
  unsigned short* wa[8];
#pragma unroll
  for (int nt = 0; nt < 2; ++nt)
#pragma unroll
    for (int rr = 0; rr < 4; ++rr) {
      int m = 4 * g + rr, n = 32 * w + 16 * nt + lm;
      wa[nt * 4 + rr] = &s_h[(m << 8) + ((((n >> 3) ^ (m & 7)) << 3) | (n & 7))];
    }
  float* ob[4] = {out, out, out, out};
  if (w < 6) {
#pragma unroll
    for (int rr = 0; rr < 4; ++rr)
      ob[rr] = out + (size_t)(r0 + 4 * g + rr) * (Lv * Vv) + 16 * w + lm;
  }

  __syncthreads();

  bf16x8 ef0, ef1;
  {
    int xi = s_x[lm];
    const unsigned short* ep = &s_emb[xi * EPAD + 8 * g];
    ef0 = *(const bf16x8*)ep;
    ef1 = *(const bf16x8*)(ep + 32);
  }

#define STEP8(TT, RB, WB, DOLOG, LAST)                                             \
  do {                                                                             \
    bf16x8 af[8];                                                                  \
    _Pragma("unroll") for (int kf = 0; kf < 8; ++kf)                               \
        af[kf] = *(const bf16x8*)(ra[kf] + (RB));                                  \
    f32x4 a0 = {bih[0], bih[0], bih[0], bih[0]};                                   \
    f32x4 a1 = {bih[1], bih[1], bih[1], bih[1]};                                   \
    a0 = __builtin_amdgcn_mfma_f32_16x16x32_bf16(ef0, wx[0][0], a0, 0, 0, 0);      \
    a1 = __builtin_amdgcn_mfma_f32_16x16x32_bf16(ef0, wx[1][0], a1, 0, 0, 0);      \
    a0 = __builtin_amdgcn_mfma_f32_16x16x32_bf16(ef1, wx[0][1], a0, 0, 0, 0);      \
    a1 = __builtin_amdgcn_mfma_f32_16x16x32_bf16(ef1, wx[1][1], a1, 0, 0, 0);      \
    _Pragma("unroll") for (int kf = 0; kf < 8; ++kf) {                             \
      a0 = __builtin_amdgcn_mfma_f32_16x16x32_bf16(af[kf], wh[0][kf], a0, 0, 0, 0);\
      a1 = __builtin_amdgcn_mfma_f32_16x16x32_bf16(af[kf], wh[1][kf], a1, 0, 0, 0);\
    }                                                                              \
    if ((DOLOG) && w < 6) {                                                        \
      f32x4 l = {bhov, bhov, bhov, bhov};                                          \
      _Pragma("unroll") for (int kf = 0; kf < 8; ++kf)                             \
          l = __builtin_amdgcn_mfma_f32_16x16x32_bf16(af[kf], who[kf], l, 0, 0, 0);\
      const size_t o = (size_t)((TT)-1) * Vv;                                      \
      ob[0][o] = l[0]; ob[1][o] = l[1]; ob[2][o] = l[2]; ob[3][o] = l[3];          \
    }                                                                              \
    {                                                                              \
      int tn = ((TT) + 1 < Lv) ? (TT) + 1 : (Lv - 1);                              \
      int xi = s_x[tn * ROWS + lm];                                                \
      const unsigned short* ep = &s_emb[xi * EPAD + 8 * g];                        \
      ef0 = *(const bf16x8*)ep;                                                    \
      ef1 = *(const bf16x8*)(ep + 32);                                             \
    }                                                                              \
    float th0 = fast_tanh(a0[0]), th1 = fast_tanh(a0[1]);                          \
    float th2 = fast_tanh(a0[2]), th3 = fast_tanh(a0[3]);                          \
    float th4 = fast_tanh(a1[0]), th5 = fast_tanh(a1[1]);                          \
    float th6 = fast_tanh(a1[2]), th7 = fast_tanh(a1[3]);                          \
    unsigned p01 = cvtpk_bf16(th0, th1), p23 = cvtpk_bf16(th2, th3);               \
    unsigned p45 = cvtpk_bf16(th4, th5), p67 = cvtpk_bf16(th6, th7);               \
    wa[0][WB] = (unsigned short)p01;                                               \
    wa[1][WB] = (unsigned short)(p01 >> 16);                                       \
    wa[2][WB] = (unsigned short)p23;                                               \
    wa[3][WB] = (unsigned short)(p23 >> 16);                                       \
    wa[4][WB] = (unsigned short)p45;                                               \
    wa[5][WB] = (unsigned short)(p45 >> 16);                                       \
    wa[6][WB] = (unsigned short)p67;                                               \
    wa[7][WB] = (unsigned short)(p67 >> 16);                                       \
    if (LAST) {                                                                    \
      float* fh = out + HOFF + (size_t)(r0 + 4 * g) * Hv + 32 * w + lm;            \
      fh[0 * Hv] = th0; fh[1 * Hv] = th1; fh[2 * Hv] = th2; fh[3 * Hv] = th3;      \
      fh[0 * Hv + 16] = th4; fh[1 * Hv + 16] = th5;                                \
      fh[2 * Hv + 16] = th6; fh[3 * Hv + 16] = th7;                                \
    }                                                                              \
    asm volatile("s_waitcnt lgkmcnt(0)\n\ts_barrier" ::: "memory");                \
    __builtin_amdgcn_sched_barrier(0);                                             \
  } while (0)

  STEP8(0, HB, 0, 0, 0);
  for (int t = 1; t < Lv - 1; t += 2) {
    STEP8(t, 0, HB, 1, 0);
    STEP8(t + 1, HB, 0, 1, 0);
  }
  STEP8(Lv - 1, 0, HB, 1, 1);

  if (w < 6) {
    bf16x8 af[8];
#pragma unroll
    for (int kf = 0; kf < 8; ++kf) af[kf] = *(const bf16x8*)(ra[kf] + HB);
    f32x4 l = {bhov, bhov, bhov, bhov};
#pragma unroll
    for (int kf = 0; kf < 8; ++kf)
      l = __builtin_amdgcn_mfma_f32_16x16x32_bf16(af[kf], who[kf], l, 0, 0, 0);
    const size_t o = (size_t)(Lv - 1) * Vv;
    ob[0][o] = l[0]; ob[1][o] = l[1]; ob[2][o] = l[2]; ob[3][o] = l[3];
  }
#undef STEP8
}

extern "C" void kernel_launch(void* const* d_in, const int* in_sizes, int n_in,
                              void* d_out, int out_size, void* d_ws, size_t ws_size,
                              hipStream_t stream) {
  const int* x     = (const int*)d_in[0];
  const float* h0  = (const float*)d_in[1];
  const float* emb = (const float*)d_in[2];
  const float* Wih = (const float*)d_in[3];
  const float* bih = (const float*)d_in[4];
  const float* Who = (const float*)d_in[5];
  const float* bho = (const float*)d_in[6];
  float* out = (float*)d_out;
  int* flag = (int*)d_ws;

  const size_t hs_bytes = (size_t)Lv * 256 * 256 * 2;  // 134.2 MB
  detect_i64<<<1, 64, 0, stream>>>(x, flag);
  if (ws_size >= hs_bytes + 256) {
    unsigned short* hsp = (unsigned short*)((char*)d_ws + 256);
    rnn4t<<<64, 512, 0, stream>>>(x, h0, emb, Wih, bih, out, hsp, flag);
    logits_gemm<<<1024, 512, 0, stream>>>(hsp, Who, bho, out);
  } else {
    rnn8<<<16, 512, 0, stream>>>(x, h0, emb, Wih, bih, Who, bho, out, flag);
  }
}

// Round 9
// 772.134 us; speedup vs baseline: 1.0317x; 1.0317x over previous
//
#include <hip/hip_runtime.h>
#include <hip/hip_bf16.h>

#define Lv 1024
#define Vv 96
#define Ev 64
#define Hv 256
#define ROWS 16
#define HOFF (256 * 1024 * 96)
#define EPAD 72
#define HB 4096   // ushorts per LDS h buffer (16 batch x 256 hidden)
#define TSL 65536 // elements per t-slice of hs (256 b x 256 h)

typedef __attribute__((ext_vector_type(8))) short bf16x8;
typedef __attribute__((ext_vector_type(4))) float f32x4;
typedef __attribute__((ext_vector_type(2))) unsigned int u32x2;

__device__ __forceinline__ unsigned short f2b(float f) {
  unsigned u = __builtin_bit_cast(unsigned, f);
  return (unsigned short)((u + 0x7fffu + ((u >> 16) & 1u)) >> 16);  // RNE
}
__device__ __forceinline__ unsigned cvtpk_bf16(float lo, float hi) {
  unsigned r;
  asm("v_cvt_pk_bf16_f32 %0, %1, %2" : "=v"(r) : "v"(lo), "v"(hi));
  return r;
}
__device__ __forceinline__ float fast_tanh(float x) {
  float e = __builtin_amdgcn_exp2f(x * 2.885390081777927f);  // exp(2x)
  return 1.0f - 2.0f * __builtin_amdgcn_rcpf(e + 1.0f);
}
// lgkm-only barrier: LDS ordered, global ops keep draining across steps.
__device__ __forceinline__ void step_barrier() {
  asm volatile("s_waitcnt lgkmcnt(0)\n\ts_barrier" ::: "memory");
  __builtin_amdgcn_sched_barrier(0);
}

__global__ void detect_i64(const int* __restrict__ x, int* __restrict__ flag) {
  if (threadIdx.x == 0 && blockIdx.x == 0) {
    int ok = 1;
    for (int i = 0; i < 64; ++i) ok &= (x[2 * i + 1] == 0);
    *flag = ok;
  }
}

// Tiny prep: emb (f32) -> embB (bf16), 96x64 = 12 KB, L1/L2-resident.
__global__ void prep_emb(const float* __restrict__ emb,
                         unsigned short* __restrict__ embB) {
  int i = blockIdx.x * 512 + threadIdx.x;
  if (i < Vv * Ev) embB[i] = f2b(emb[i]);
}

// ================= Path A loop: rnn8g (R5 + global bf16 emb) =================
// Transposed recurrence h_t^T = tanh(Wh^T·h^T + Wx^T·emb^T + b), 16 WGs x 16
// batch cols, 8 waves (2/SIMD). Identical to the R5-proven rnn8t EXCEPT the
// emb B-fragments load from global embB (L1-hit, vmem pipe) instead of LDS —
// removes 2 of 10 ds_read_b128 per wave per step and the random-row emb
// bank-conflicts. hs[t][b][h] exported for the deferred logits GEMM.
__global__ __launch_bounds__(512, 2) void rnn8g(
    const int* __restrict__ x, const float* __restrict__ h0,
    const float* __restrict__ W_ih, const float* __restrict__ b_ih,
    float* __restrict__ out, const unsigned short* __restrict__ embB,
    unsigned short* __restrict__ hs, const int* __restrict__ flagp) {
  const int tid = threadIdx.x;
  const int w = tid >> 6, ln = tid & 63, lm = ln & 15, g = ln >> 4;
  const int r0 = blockIdx.x * ROWS;

  __shared__ __attribute__((aligned(16))) unsigned short s_h[2 * HB];
  __shared__ unsigned char s_x[Lv * ROWS];

  const int flag = *flagp;  // 1 => x is int64

  for (int idx = tid; idx < ROWS * Hv; idx += 512) {  // h_{-1} -> buf1
    int b_ = idx >> 8, hd = idx & 255;
    s_h[HB + b_ * 256 + ((((hd >> 3) ^ (b_ & 7)) << 3) | (hd & 7))] =
        f2b(h0[(r0 + b_) * Hv + hd]);
  }
  for (int idx = tid; idx < ROWS * Lv; idx += 512) {  // x, transposed u8
    int t = idx >> 4, row = idx & 15;
    long long src = (long long)(r0 + row) * Lv + t;
    int v = flag ? x[2 * src] : x[src];
    s_x[t * ROWS + row] = (unsigned char)v;
  }

  bf16x8 wh[2][8], wx[2][2];
  f32x4 bihv[2];
#pragma unroll
  for (int nt = 0; nt < 2; ++nt) {
    const int n = 32 * w + 16 * nt + lm;  // output hidden row (A-frag row)
#pragma unroll
    for (int kf = 0; kf < 8; ++kf)
#pragma unroll
      for (int i = 0; i < 8; ++i)
        wh[nt][kf][i] = (short)f2b(W_ih[(Ev + 32 * kf + 8 * g + i) * Hv + n]);
#pragma unroll
    for (int kf = 0; kf < 2; ++kf)
#pragma unroll
      for (int i = 0; i < 8; ++i)
        wx[nt][kf][i] = (short)f2b(W_ih[(32 * kf + 8 * g + i) * Hv + n]);
    bihv[nt] = *(const f32x4*)&b_ih[32 * w + 16 * nt + 4 * g];
  }

  const unsigned short* ra[8];  // B-frag reads: batch col lm, k = 32kf+8g+i
#pragma unroll
  for (int kf = 0; kf < 8; ++kf)
    ra[kf] = &s_h[lm * 256 + (((4 * kf + g) ^ (lm & 7)) << 3)];
  unsigned short* wa[2];  // b64 writes: hidden 32w+16nt+4g, batch lm
#pragma unroll
  for (int nt = 0; nt < 2; ++nt)
    wa[nt] = &s_h[lm * 256 + (((4 * w + 2 * nt + (g >> 1)) ^ (lm & 7)) << 3) +
                  ((g & 1) << 2)];
  unsigned short* hp = hs + (size_t)(r0 + lm) * 256 + 32 * w + 4 * g;  // t=0

  __syncthreads();

  bf16x8 ef0, ef1;  // emb B-frags for current step (from global embB)
  int xi_n;
  {
    int xi0 = s_x[lm];
    const unsigned short* ep = embB + xi0 * 64 + 8 * g;
    ef0 = *(const bf16x8*)ep;
    ef1 = *(const bf16x8*)(ep + 32);
    xi_n = s_x[ROWS + lm];  // t=1
  }

#define STEP(TT, RB, WB, LAST)                                                    \
  do {                                                                            \
    bf16x8 af[8];                                                                 \
    _Pragma("unroll") for (int kf = 0; kf < 8; ++kf)                              \
        af[kf] = *(const bf16x8*)(ra[kf] + (RB));                                 \
    f32x4 aA0 = bihv[0], aA1 = bihv[1];                                           \
    f32x4 aB0 = {0.f, 0.f, 0.f, 0.f}, aB1 = {0.f, 0.f, 0.f, 0.f};                 \
    aA0 = __builtin_amdgcn_mfma_f32_16x16x32_bf16(wx[0][0], ef0, aA0, 0, 0, 0);   \
    aA1 = __builtin_amdgcn_mfma_f32_16x16x32_bf16(wx[1][0], ef0, aA1, 0, 0, 0);   \
    aB0 = __builtin_amdgcn_mfma_f32_16x16x32_bf16(wx[0][1], ef1, aB0, 0, 0, 0);   \
    aB1 = __builtin_amdgcn_mfma_f32_16x16x32_bf16(wx[1][1], ef1, aB1, 0, 0, 0);   \
    _Pragma("unroll") for (int kf = 0; kf < 4; ++kf) {                            \
      aA0 = __builtin_amdgcn_mfma_f32_16x16x32_bf16(wh[0][kf], af[kf], aA0, 0, 0, 0); \
      aA1 = __builtin_amdgcn_mfma_f32_16x16x32_bf16(wh[1][kf], af[kf], aA1, 0, 0, 0); \
    }                                                                             \
    _Pragma("unroll") for (int kf = 4; kf < 8; ++kf) {                            \
      aB0 = __builtin_amdgcn_mfma_f32_16x16x32_bf16(wh[0][kf], af[kf], aB0, 0, 0, 0); \
      aB1 = __builtin_amdgcn_mfma_f32_16x16x32_bf16(wh[1][kf], af[kf], aB1, 0, 0, 0); \
    }                                                                             \
    { /* prefetch emb frags for TT+1 (global, hidden under this step) */          \
      const unsigned short* ep = embB + xi_n * 64 + 8 * g;                        \
      ef0 = *(const bf16x8*)ep;                                                   \
      ef1 = *(const bf16x8*)(ep + 32);                                            \
      int tn = ((TT) + 2 < Lv) ? (TT) + 2 : (Lv - 1);                             \
      xi_n = s_x[tn * ROWS + lm];                                                 \
    }                                                                             \
    float h0v = fast_tanh(aA0[0] + aB0[0]), h1v = fast_tanh(aA0[1] + aB0[1]);     \
    float h2v = fast_tanh(aA0[2] + aB0[2]), h3v = fast_tanh(aA0[3] + aB0[3]);     \
    float h4v = fast_tanh(aA1[0] + aB1[0]), h5v = fast_tanh(aA1[1] + aB1[1]);     \
    float h6v = fast_tanh(aA1[2] + aB1[2]), h7v = fast_tanh(aA1[3] + aB1[3]);     \
    u32x2 p0, p1;                                                                 \
    p0[0] = cvtpk_bf16(h0v, h1v);                                                 \
    p0[1] = cvtpk_bf16(h2v, h3v);                                                 \
    p1[0] = cvtpk_bf16(h4v, h5v);                                                 \
    p1[1] = cvtpk_bf16(h6v, h7v);                                                 \
    *(u32x2*)(wa[0] + (WB)) = p0;                                                 \
    *(u32x2*)(wa[1] + (WB)) = p1;                                                 \
    *(u32x2*)hp = p0;        /* hs[TT], nt=0 */                                   \
    *(u32x2*)(hp + 16) = p1; /* hs[TT], nt=1 */                                   \
    hp += TSL;                                                                    \
    if (LAST) {                                                                   \
      float* fo = out + HOFF + (size_t)(r0 + lm) * Hv + 32 * w + 4 * g;           \
      *(f32x4*)fo = (f32x4){h0v, h1v, h2v, h3v};                                  \
      *(f32x4*)(fo + 16) = (f32x4){h4v, h5v, h6v, h7v};                           \
    }                                                                             \
    step_barrier();                                                               \
  } while (0)

  STEP(0, HB, 0, 0);  // h_{-1}(buf1) -> h_0(buf0), export hs[0]
  for (int t = 1; t < Lv - 1; t += 2) {
    STEP(t, 0, HB, 0);
    STEP(t + 1, HB, 0, 0);
  }
  STEP(Lv - 1, 0, HB, 1);  // hs[1023] + final hidden fp32
#undef STEP
}

// ============== Path B loop: rnn8t (R5 verbatim, proven PASS) ==============
__global__ __launch_bounds__(512, 2) void rnn8t(
    const int* __restrict__ x, const float* __restrict__ h0,
    const float* __restrict__ emb, const float* __restrict__ W_ih,
    const float* __restrict__ b_ih, float* __restrict__ out,
    unsigned short* __restrict__ hs, const int* __restrict__ flagp) {
  const int tid = threadIdx.x;
  const int w = tid >> 6, ln = tid & 63, lm = ln & 15, g = ln >> 4;
  const int r0 = blockIdx.x * ROWS;

  __shared__ __attribute__((aligned(16))) unsigned short s_h[2 * HB];
  __shared__ __attribute__((aligned(16))) unsigned short s_emb[Vv * EPAD];
  __shared__ unsigned char s_x[Lv * ROWS];

  const int flag = *flagp;

  for (int idx = tid; idx < Vv * Ev; idx += 512)
    s_emb[(idx >> 6) * EPAD + (idx & 63)] = f2b(emb[idx]);
  for (int idx = tid; idx < ROWS * Hv; idx += 512) {
    int b_ = idx >> 8, hd = idx & 255;
    s_h[HB + b_ * 256 + ((((hd >> 3) ^ (b_ & 7)) << 3) | (hd & 7))] =
        f2b(h0[(r0 + b_) * Hv + hd]);
  }
  for (int idx = tid; idx < ROWS * Lv; idx += 512) {
    int t = idx >> 4, row = idx & 15;
    long long src = (long long)(r0 + row) * Lv + t;
    int v = flag ? x[2 * src] : x[src];
    s_x[t * ROWS + row] = (unsigned char)v;
  }

  bf16x8 wh[2][8], wx[2][2];
  f32x4 bihv[2];
#pragma unroll
  for (int nt = 0; nt < 2; ++nt) {
    const int n = 32 * w + 16 * nt + lm;
#pragma unroll
    for (int kf = 0; kf < 8; ++kf)
#pragma unroll
      for (int i = 0; i < 8; ++i)
        wh[nt][kf][i] = (short)f2b(W_ih[(Ev + 32 * kf + 8 * g + i) * Hv + n]);
#pragma unroll
    for (int kf = 0; kf < 2; ++kf)
#pragma unroll
      for (int i = 0; i < 8; ++i)
        wx[nt][kf][i] = (short)f2b(W_ih[(32 * kf + 8 * g + i) * Hv + n]);
    bihv[nt] = *(const f32x4*)&b_ih[32 * w + 16 * nt + 4 * g];
  }

  const unsigned short* ra[8];
#pragma unroll
  for (int kf = 0; kf < 8; ++kf)
    ra[kf] = &s_h[lm * 256 + (((4 * kf + g) ^ (lm & 7)) << 3)];
  unsigned short* wa[2];
#pragma unroll
  for (int nt = 0; nt < 2; ++nt)
    wa[nt] = &s_h[lm * 256 + (((4 * w + 2 * nt + (g >> 1)) ^ (lm & 7)) << 3) +
                  ((g & 1) << 2)];
  unsigned short* hp = hs + (size_t)(r0 + lm) * 256 + 32 * w + 4 * g;

  __syncthreads();

  bf16x8 ef0, ef1;
  int xi_n;
  {
    int xi0 = s_x[lm];
    const unsigned short* ep = &s_emb[xi0 * EPAD + 8 * g];
    ef0 = *(const bf16x8*)ep;
    ef1 = *(const bf16x8*)(ep + 32);
    xi_n = s_x[ROWS + lm];
  }

#define STEPB(TT, RB, WB, LAST)                                                   \
  do {                                                                            \
    bf16x8 af[8];                                                                 \
    _Pragma("unroll") for (int kf = 0; kf < 8; ++kf)                              \
        af[kf] = *(const bf16x8*)(ra[kf] + (RB));                                 \
    f32x4 aA0 = bihv[0], aA1 = bihv[1];                                           \
    f32x4 aB0 = {0.f, 0.f, 0.f, 0.f}, aB1 = {0.f, 0.f, 0.f, 0.f};                 \
    aA0 = __builtin_amdgcn_mfma_f32_16x16x32_bf16(wx[0][0], ef0, aA0, 0, 0, 0);   \
    aA1 = __builtin_amdgcn_mfma_f32_16x16x32_bf16(wx[1][0], ef0, aA1, 0, 0, 0);   \
    aB0 = __builtin_amdgcn_mfma_f32_16x16x32_bf16(wx[0][1], ef1, aB0, 0, 0, 0);   \
    aB1 = __builtin_amdgcn_mfma_f32_16x16x32_bf16(wx[1][1], ef1, aB1, 0, 0, 0);   \
    _Pragma("unroll") for (int kf = 0; kf < 4; ++kf) {                            \
      aA0 = __builtin_amdgcn_mfma_f32_16x16x32_bf16(wh[0][kf], af[kf], aA0, 0, 0, 0); \
      aA1 = __builtin_amdgcn_mfma_f32_16x16x32_bf16(wh[1][kf], af[kf], aA1, 0, 0, 0); \
    }                                                                             \
    _Pragma("unroll") for (int kf = 4; kf < 8; ++kf) {                            \
      aB0 = __builtin_amdgcn_mfma_f32_16x16x32_bf16(wh[0][kf], af[kf], aB0, 0, 0, 0); \
      aB1 = __builtin_amdgcn_mfma_f32_16x16x32_bf16(wh[1][kf], af[kf], aB1, 0, 0, 0); \
    }                                                                             \
    {                                                                             \
      const unsigned short* ep = &s_emb[xi_n * EPAD + 8 * g];                     \
      ef0 = *(const bf16x8*)ep;                                                   \
      ef1 = *(const bf16x8*)(ep + 32);                                            \
      int tn = ((TT) + 2 < Lv) ? (TT) + 2 : (Lv - 1);                             \
      xi_n = s_x[tn * ROWS + lm];                                                 \
    }                                                                             \
    float h0v = fast_tanh(aA0[0] + aB0[0]), h1v = fast_tanh(aA0[1] + aB0[1]);     \
    float h2v = fast_tanh(aA0[2] + aB0[2]), h3v = fast_tanh(aA0[3] + aB0[3]);     \
    float h4v = fast_tanh(aA1[0] + aB1[0]), h5v = fast_tanh(aA1[1] + aB1[1]);     \
    float h6v = fast_tanh(aA1[2] + aB1[2]), h7v = fast_tanh(aA1[3] + aB1[3]);     \
    u32x2 p0, p1;                                                                 \
    p0[0] = cvtpk_bf16(h0v, h1v);                                                 \
    p0[1] = cvtpk_bf16(h2v, h3v);                                                 \
    p1[0] = cvtpk_bf16(h4v, h5v);                                                 \
    p1[1] = cvtpk_bf16(h6v, h7v);                                                 \
    *(u32x2*)(wa[0] + (WB)) = p0;                                                 \
    *(u32x2*)(wa[1] + (WB)) = p1;                                                 \
    *(u32x2*)hp = p0;                                                             \
    *(u32x2*)(hp + 16) = p1;                                                      \
    hp += TSL;                                                                    \
    if (LAST) {                                                                   \
      float* fo = out + HOFF + (size_t)(r0 + lm) * Hv + 32 * w + 4 * g;           \
      *(f32x4*)fo = (f32x4){h0v, h1v, h2v, h3v};                                  \
      *(f32x4*)(fo + 16) = (f32x4){h4v, h5v, h6v, h7v};                           \
    }                                                                             \
    step_barrier();                                                               \
  } while (0)

  STEPB(0, HB, 0, 0);
  for (int t = 1; t < Lv - 1; t += 2) {
    STEPB(t, 0, HB, 0);
    STEPB(t + 1, HB, 0, 0);
  }
  STEPB(Lv - 1, 0, HB, 1);
#undef STEPB
}

// Deferred logits: out[b][t][v] = hs[t][b][:]@W_ho + b_ho, full chip.
__global__ __launch_bounds__(512, 2) void logits_gemm(
    const unsigned short* __restrict__ hs, const float* __restrict__ W_ho,
    const float* __restrict__ b_ho, float* __restrict__ out) {
  const int tid = threadIdx.x;
  const int w = tid >> 6, ln = tid & 63, lm = ln & 15, g = ln >> 4;
  const int tg = blockIdx.x >> 2, bg = blockIdx.x & 3;

  __shared__ __attribute__((aligned(16))) unsigned short s_who[3072 * 8];
  for (int f = tid; f < 3072; f += 512) {
    int vt = f >> 9, kf = (f >> 6) & 7, lane = f & 63;
    int k0 = 32 * kf + 8 * (lane >> 4), v = 16 * vt + (lane & 15);
    bf16x8 fr;
#pragma unroll
    for (int i = 0; i < 8; ++i) fr[i] = (short)f2b(W_ho[(k0 + i) * Vv + v]);
    *(bf16x8*)&s_who[f * 8] = fr;
  }
  __syncthreads();

  const int bt = w & 3, vg = w >> 2;
  const int b0 = bg * 64 + bt * 16;
  const int j0 = vg * 3;
  float bb[3];
#pragma unroll
  for (int jj = 0; jj < 3; ++jj) bb[jj] = b_ho[16 * (j0 + jj) + lm];

#pragma unroll
  for (int tt = 0; tt < 4; ++tt) {
    const int t = tg * 4 + tt;
    const unsigned short* hpb = hs + (size_t)t * TSL + (b0 + lm) * 256 + 8 * g;
    f32x4 acc[3];
#pragma unroll
    for (int jj = 0; jj < 3; ++jj)
      acc[jj] = (f32x4){bb[jj], bb[jj], bb[jj], bb[jj]};
#pragma unroll
    for (int kf = 0; kf < 8; ++kf) {
      bf16x8 af = *(const bf16x8*)(hpb + 32 * kf);
#pragma unroll
      for (int jj = 0; jj < 3; ++jj) {
        bf16x8 bw = *(const bf16x8*)&s_who[(((j0 + jj) * 8 + kf) * 64 + ln) * 8];
        acc[jj] =
            __builtin_amdgcn_mfma_f32_16x16x32_bf16(af, bw, acc[jj], 0, 0, 0);
      }
    }
#pragma unroll
    for (int jj = 0; jj < 3; ++jj)
#pragma unroll
      for (int rr = 0; rr < 4; ++rr)
        out[(size_t)(b0 + 4 * g + rr) * (Lv * Vv) + (size_t)t * Vv +
            16 * (j0 + jj) + lm] = acc[jj][rr];
  }
}

// ===================== Path C fallback (R2 kernel, proven) =====================
__global__ __launch_bounds__(512, 2) void rnn8(
    const int* __restrict__ x, const float* __restrict__ h0,
    const float* __restrict__ emb, const float* __restrict__ W_ih,
    const float* __restrict__ b_ih, const float* __restrict__ W_ho,
    const float* __restrict__ b_ho, float* __restrict__ out,
    const int* __restrict__ flagp) {
  const int tid = threadIdx.x;
  const int w = tid >> 6, ln = tid & 63, lm = ln & 15, g = ln >> 4;
  const int r0 = blockIdx.x * ROWS;

  __shared__ __attribute__((aligned(16))) unsigned short s_emb[Vv * EPAD];
  __shared__ __attribute__((aligned(16))) unsigned short s_h[2 * HB];
  __shared__ unsigned char s_x[Lv * ROWS];

  const int flag = *flagp;

  for (int idx = tid; idx < Vv * Ev; idx += 512)
    s_emb[(idx >> 6) * EPAD + (idx & 63)] = f2b(emb[idx]);
  for (int idx = tid; idx < ROWS * Hv; idx += 512) {
    int m = idx >> 8, nn = idx & 255;
    s_h[HB + (m << 8) + ((((nn >> 3) ^ (m & 7)) << 3) | (nn & 7))] =
        f2b(h0[(r0 + m) * Hv + nn]);
  }
  for (int idx = tid; idx < ROWS * Lv; idx += 512) {
    int row = idx >> 10, t = idx & 1023;
    long long src = (long long)(r0 + row) * Lv + t;
    int v = flag ? x[2 * src] : x[src];
    s_x[t * ROWS + row] = (unsigned char)v;
  }

  bf16x8 wh[2][8], wx[2][2], who[8];
  float bih[2], bhov = 0.0f;
#pragma unroll
  for (int nt = 0; nt < 2; ++nt) {
    const int n = 32 * w + 16 * nt + lm;
    bih[nt] = b_ih[n];
#pragma unroll
    for (int kf = 0; kf < 8; ++kf)
#pragma unroll
      for (int i = 0; i < 8; ++i)
        wh[nt][kf][i] = (short)f2b(W_ih[(Ev + 32 * kf + 8 * g + i) * Hv + n]);
#pragma unroll
    for (int kf = 0; kf < 2; ++kf)
#pragma unroll
      for (int i = 0; i < 8; ++i)
        wx[nt][kf][i] = (short)f2b(W_ih[(32 * kf + 8 * g + i) * Hv + n]);
  }
  if (w < 6) {
    const int n = 16 * w + lm;
    bhov = b_ho[n];
#pragma unroll
    for (int kf = 0; kf < 8; ++kf)
#pragma unroll
      for (int i = 0; i < 8; ++i)
        who[kf][i] = (short)f2b(W_ho[(32 * kf + 8 * g + i) * Vv + n]);
  }

  const unsigned short* ra[8];
#pragma unroll
  for (int kf = 0; kf < 8; ++kf)
    ra[kf] = &s_h[(lm << 8) + (((4 * kf + g) ^ (lm & 7)) << 3)];
  unsigned short* wa[8];
#pragma unroll
  for (int nt = 0; nt < 2; ++nt)
#pragma unroll
    for (int rr = 0; rr < 4; ++rr) {
      int m = 4 * g + rr, n = 32 * w + 16 * nt + lm;
      wa[nt * 4 + rr] = &s_h[(m << 8) + ((((n >> 3) ^ (m & 7)) << 3) | (n & 7))];
    }
  float* ob[4] = {out, out, out, out};
  if (w < 6) {
#pragma unroll
    for (int rr = 0; rr < 4; ++rr)
      ob[rr] = out + (size_t)(r0 + 4 * g + rr) * (Lv * Vv) + 16 * w + lm;
  }

  __syncthreads();

  bf16x8 ef0, ef1;
  {
    int xi = s_x[lm];
    const unsigned short* ep = &s_emb[xi * EPAD + 8 * g];
    ef0 = *(const bf16x8*)ep;
    ef1 = *(const bf16x8*)(ep + 32);
  }

#define STEP8(TT, RB, WB, DOLOG, LAST)                                             \
  do {                                                                             \
    bf16x8 af[8];                                                                  \
    _Pragma("unroll") for (int kf = 0; kf < 8; ++kf)                               \
        af[kf] = *(const bf16x8*)(ra[kf] + (RB));                                  \
    f32x4 a0 = {bih[0], bih[0], bih[0], bih[0]};                                   \
    f32x4 a1 = {bih[1], bih[1], bih[1], bih[1]};                                   \
    a0 = __builtin_amdgcn_mfma_f32_16x16x32_bf16(ef0, wx[0][0], a0, 0, 0, 0);      \
    a1 = __builtin_amdgcn_mfma_f32_16x16x32_bf16(ef0, wx[1][0], a1, 0, 0, 0);      \
    a0 = __builtin_amdgcn_mfma_f32_16x16x32_bf16(ef1, wx[0][1], a0, 0, 0, 0);      \
    a1 = __builtin_amdgcn_mfma_f32_16x16x32_bf16(ef1, wx[1][1], a1, 0, 0, 0);      \
    _Pragma("unroll") for (int kf = 0; kf < 8; ++kf) {                             \
      a0 = __builtin_amdgcn_mfma_f32_16x16x32_bf16(af[kf], wh[0][kf], a0, 0, 0, 0);\
      a1 = __builtin_amdgcn_mfma_f32_16x16x32_bf16(af[kf], wh[1][kf], a1, 0, 0, 0);\
    }                                                                              \
    if ((DOLOG) && w < 6) {                                                        \
      f32x4 l = {bhov, bhov, bhov, bhov};                                          \
      _Pragma("unroll") for (int kf = 0; kf < 8; ++kf)                             \
          l = __builtin_amdgcn_mfma_f32_16x16x32_bf16(af[kf], who[kf], l, 0, 0, 0);\
      const size_t o = (size_t)((TT)-1) * Vv;                                      \
      ob[0][o] = l[0]; ob[1][o] = l[1]; ob[2][o] = l[2]; ob[3][o] = l[3];          \
    }                                                                              \
    {                                                                              \
      int tn = ((TT) + 1 < Lv) ? (TT) + 1 : (Lv - 1);                              \
      int xi = s_x[tn * ROWS + lm];                                                \
      const unsigned short* ep = &s_emb[xi * EPAD + 8 * g];                        \
      ef0 = *(const bf16x8*)ep;                                                    \
      ef1 = *(const bf16x8*)(ep + 32);                                             \
    }                                                                              \
    float th0 = fast_tanh(a0[0]), th1 = fast_tanh(a0[1]);                          \
    float th2 = fast_tanh(a0[2]), th3 = fast_tanh(a0[3]);                          \
    float th4 = fast_tanh(a1[0]), th5 = fast_tanh(a1[1]);                          \
    float th6 = fast_tanh(a1[2]), th7 = fast_tanh(a1[3]);                          \
    unsigned p01 = cvtpk_bf16(th0, th1), p23 = cvtpk_bf16(th2, th3);               \
    unsigned p45 = cvtpk_bf16(th4, th5), p67 = cvtpk_bf16(th6, th7);               \
    wa[0][WB] = (unsigned short)p01;                                               \
    wa[1][WB] = (unsigned short)(p01 >> 16);                                       \
    wa[2][WB] = (unsigned short)p23;                                               \
    wa[3][WB] = (unsigned short)(p23 >> 16);                                       \
    wa[4][WB] = (unsigned short)p45;                                               \
    wa[5][WB] = (unsigned short)(p45 >> 16);                                       \
    wa[6][WB] = (unsigned short)p67;                                               \
    wa[7][WB] = (unsigned short)(p67 >> 16);                                       \
    if (LAST) {                                                                    \
      float* fh = out + HOFF + (size_t)(r0 + 4 * g) * Hv + 32 * w + lm;            \
      fh[0 * Hv] = th0; fh[1 * Hv] = th1; fh[2 * Hv] = th2; fh[3 * Hv] = th3;      \
      fh[0 * Hv + 16] = th4; fh[1 * Hv + 16] = th5;                                \
      fh[2 * Hv + 16] = th6; fh[3 * Hv + 16] = th7;                                \
    }                                                                              \
    asm volatile("s_waitcnt lgkmcnt(0)\n\ts_barrier" ::: "memory");                \
    __builtin_amdgcn_sched_barrier(0);                                             \
  } while (0)

  STEP8(0, HB, 0, 0, 0);
  for (int t = 1; t < Lv - 1; t += 2) {
    STEP8(t, 0, HB, 1, 0);
    STEP8(t + 1, HB, 0, 1, 0);
  }
  STEP8(Lv - 1, 0, HB, 1, 1);

  if (w < 6) {
    bf16x8 af[8];
#pragma unroll
    for (int kf = 0; kf < 8; ++kf) af[kf] = *(const bf16x8*)(ra[kf] + HB);
    f32x4 l = {bhov, bhov, bhov, bhov};
#pragma unroll
    for (int kf = 0; kf < 8; ++kf)
      l = __builtin_amdgcn_mfma_f32_16x16x32_bf16(af[kf], who[kf], l, 0, 0, 0);
    const size_t o = (size_t)(Lv - 1) * Vv;
    ob[0][o] = l[0]; ob[1][o] = l[1]; ob[2][o] = l[2]; ob[3][o] = l[3];
  }
#undef STEP8
}

extern "C" void kernel_launch(void* const* d_in, const int* in_sizes, int n_in,
                              void* d_out, int out_size, void* d_ws, size_t ws_size,
                              hipStream_t stream) {
  const int* x     = (const int*)d_in[0];
  const float* h0  = (const float*)d_in[1];
  const float* emb = (const float*)d_in[2];
  const float* Wih = (const float*)d_in[3];
  const float* bih = (const float*)d_in[4];
  const float* Who = (const float*)d_in[5];
  const float* bho = (const float*)d_in[6];
  float* out = (float*)d_out;
  int* flag = (int*)d_ws;

  const size_t hs_bytes = (size_t)Lv * 256 * 256 * 2;  // 134.2 MB
  detect_i64<<<1, 64, 0, stream>>>(x, flag);
  if (ws_size >= hs_bytes + 16384) {
    // Path A: global bf16 emb table + R5 loop + deferred logits.
    unsigned short* embB = (unsigned short*)((char*)d_ws + 256);
    unsigned short* hs   = (unsigned short*)((char*)d_ws + 16384);
    prep_emb<<<12, 512, 0, stream>>>(emb, embB);
    rnn8g<<<16, 512, 0, stream>>>(x, h0, Wih, bih, out, embB, hs, flag);
    logits_gemm<<<1024, 512, 0, stream>>>(hs, Who, bho, out);
  } else if (ws_size >= hs_bytes + 256) {
    // Path B: R5 verbatim.
    unsigned short* hs = (unsigned short*)((char*)d_ws + 256);
    rnn8t<<<16, 512, 0, stream>>>(x, h0, emb, Wih, bih, out, hs, flag);
    logits_gemm<<<1024, 512, 0, stream>>>(hs, Who, bho, out);
  } else {
    rnn8<<<16, 512, 0, stream>>>(x, h0, emb, Wih, bih, Who, bho, out, flag);
  }
}

// Round 10
// 651.048 us; speedup vs baseline: 1.2235x; 1.1860x over previous
//
#include <hip/hip_runtime.h>
#include <hip/hip_bf16.h>

#define Lv 1024
#define Vv 96
#define Ev 64
#define Hv 256
#define ROWS 16
#define HOFF (256 * 1024 * 96)
#define EPAD 72
#define HB 4096   // ushorts per LDS h buffer (16 batch x 256 hidden)
#define TSL 65536 // elements per t-slice of hs (256 b x 256 h)

typedef __attribute__((ext_vector_type(8))) short bf16x8;
typedef __attribute__((ext_vector_type(4))) float f32x4;
typedef __attribute__((ext_vector_type(2))) unsigned int u32x2;

__device__ __forceinline__ unsigned short f2b(float f) {
  unsigned u = __builtin_bit_cast(unsigned, f);
  return (unsigned short)((u + 0x7fffu + ((u >> 16) & 1u)) >> 16);  // RNE
}
__device__ __forceinline__ unsigned cvtpk_bf16(float lo, float hi) {
  unsigned r;
  asm("v_cvt_pk_bf16_f32 %0, %1, %2" : "=v"(r) : "v"(lo), "v"(hi));
  return r;
}
__device__ __forceinline__ float fast_tanh(float x) {
  float e = __builtin_amdgcn_exp2f(x * 2.885390081777927f);  // exp(2x)
  return 1.0f - 2.0f * __builtin_amdgcn_rcpf(e + 1.0f);
}
// lgkm-only barrier: LDS ordered, global ops keep draining across steps.
__device__ __forceinline__ void step_barrier() {
  asm volatile("s_waitcnt lgkmcnt(0)\n\ts_barrier" ::: "memory");
  __builtin_amdgcn_sched_barrier(0);
}

__global__ void detect_i64(const int* __restrict__ x, int* __restrict__ flag) {
  if (threadIdx.x == 0 && blockIdx.x == 0) {
    int ok = 1;
    for (int i = 0; i < 64; ++i) ok &= (x[2 * i + 1] == 0);
    *flag = ok;
  }
}

// ==================== primary loop: rnn8t (R5 + split-nt chains) ====================
// Transposed recurrence h_t^T = tanh(Wh^T·h^T + Wx^T·emb^T + b), 16 WGs x 16
// batch cols, 8 waves (2/SIMD). Per step, per wave, TWO independent full-K
// MFMA chains (nt=0 hidden rows 32w..+16, nt=1 rows 32w+16..+32); nt0's
// tanh/pack/writes retire UNDER nt1's MFMAs (tail overlap). Memory pattern
// identical to the R5-proven kernel. hs[t][b][h] exported for deferred logits.
__global__ __launch_bounds__(512, 2) void rnn8t(
    const int* __restrict__ x, const float* __restrict__ h0,
    const float* __restrict__ emb, const float* __restrict__ W_ih,
    const float* __restrict__ b_ih, float* __restrict__ out,
    unsigned short* __restrict__ hs, const int* __restrict__ flagp) {
  const int tid = threadIdx.x;
  const int w = tid >> 6, ln = tid & 63, lm = ln & 15, g = ln >> 4;
  const int r0 = blockIdx.x * ROWS;

  __shared__ __attribute__((aligned(16))) unsigned short s_h[2 * HB];
  __shared__ __attribute__((aligned(16))) unsigned short s_emb[Vv * EPAD];
  __shared__ unsigned char s_x[Lv * ROWS];

  const int flag = *flagp;  // 1 => x is int64

  for (int idx = tid; idx < Vv * Ev; idx += 512)
    s_emb[(idx >> 6) * EPAD + (idx & 63)] = f2b(emb[idx]);
  for (int idx = tid; idx < ROWS * Hv; idx += 512) {  // h_{-1} -> buf1
    int b_ = idx >> 8, hd = idx & 255;
    s_h[HB + b_ * 256 + ((((hd >> 3) ^ (b_ & 7)) << 3) | (hd & 7))] =
        f2b(h0[(r0 + b_) * Hv + hd]);
  }
  for (int idx = tid; idx < ROWS * Lv; idx += 512) {  // x, transposed u8
    int t = idx >> 4, row = idx & 15;
    long long src = (long long)(r0 + row) * Lv + t;
    int v = flag ? x[2 * src] : x[src];
    s_x[t * ROWS + row] = (unsigned char)v;
  }

  bf16x8 wh[2][8], wx[2][2];  // A-frags: rows 32w+16nt+lm, k = 32kf+8g+i
  f32x4 bihv[2];
#pragma unroll
  for (int nt = 0; nt < 2; ++nt) {
    const int n = 32 * w + 16 * nt + lm;
#pragma unroll
    for (int kf = 0; kf < 8; ++kf)
#pragma unroll
      for (int i = 0; i < 8; ++i)
        wh[nt][kf][i] = (short)f2b(W_ih[(Ev + 32 * kf + 8 * g + i) * Hv + n]);
#pragma unroll
    for (int kf = 0; kf < 2; ++kf)
#pragma unroll
      for (int i = 0; i < 8; ++i)
        wx[nt][kf][i] = (short)f2b(W_ih[(32 * kf + 8 * g + i) * Hv + n]);
    bihv[nt] = *(const f32x4*)&b_ih[32 * w + 16 * nt + 4 * g];
  }

  const unsigned short* ra[8];  // B-frag reads: batch col lm, k = 32kf+8g+i
#pragma unroll
  for (int kf = 0; kf < 8; ++kf)
    ra[kf] = &s_h[lm * 256 + (((4 * kf + g) ^ (lm & 7)) << 3)];
  unsigned short* wa[2];  // b64 writes: hidden 32w+16nt+4g, batch lm
#pragma unroll
  for (int nt = 0; nt < 2; ++nt)
    wa[nt] = &s_h[lm * 256 + (((4 * w + 2 * nt + (g >> 1)) ^ (lm & 7)) << 3) +
                  ((g & 1) << 2)];
  unsigned short* hp = hs + (size_t)(r0 + lm) * 256 + 32 * w + 4 * g;  // t=0

  __syncthreads();

  bf16x8 ef0, ef1;  // emb B-frags for current step
  int xi_n;
  {
    int xi0 = s_x[lm];
    const unsigned short* ep = &s_emb[xi0 * EPAD + 8 * g];
    ef0 = *(const bf16x8*)ep;
    ef1 = *(const bf16x8*)(ep + 32);
    xi_n = s_x[ROWS + lm];  // t=1
  }

#define STEPB(TT, RB, WB, LAST)                                                   \
  do {                                                                            \
    bf16x8 af[8];                                                                 \
    _Pragma("unroll") for (int kf = 0; kf < 8; ++kf)                              \
        af[kf] = *(const bf16x8*)(ra[kf] + (RB));                                 \
    /* ---- chain nt=0 (full K, single accumulator) ---- */                       \
    f32x4 a0 = bihv[0];                                                           \
    a0 = __builtin_amdgcn_mfma_f32_16x16x32_bf16(wx[0][0], ef0, a0, 0, 0, 0);     \
    a0 = __builtin_amdgcn_mfma_f32_16x16x32_bf16(wx[0][1], ef1, a0, 0, 0, 0);     \
    _Pragma("unroll") for (int kf = 0; kf < 8; ++kf)                              \
        a0 = __builtin_amdgcn_mfma_f32_16x16x32_bf16(wh[0][kf], af[kf], a0, 0, 0, 0); \
    float h0v = fast_tanh(a0[0]), h1v = fast_tanh(a0[1]);                         \
    float h2v = fast_tanh(a0[2]), h3v = fast_tanh(a0[3]);                         \
    u32x2 p0;                                                                     \
    p0[0] = cvtpk_bf16(h0v, h1v);                                                 \
    p0[1] = cvtpk_bf16(h2v, h3v);                                                 \
    *(u32x2*)(wa[0] + (WB)) = p0; /* retires under nt1's MFMAs */                 \
    *(u32x2*)hp = p0;             /* hs[TT], nt=0 */                              \
    /* ---- chain nt=1 ---- */                                                    \
    f32x4 a1 = bihv[1];                                                           \
    a1 = __builtin_amdgcn_mfma_f32_16x16x32_bf16(wx[1][0], ef0, a1, 0, 0, 0);     \
    a1 = __builtin_amdgcn_mfma_f32_16x16x32_bf16(wx[1][1], ef1, a1, 0, 0, 0);     \
    _Pragma("unroll") for (int kf = 0; kf < 8; ++kf)                              \
        a1 = __builtin_amdgcn_mfma_f32_16x16x32_bf16(wh[1][kf], af[kf], a1, 0, 0, 0); \
    { /* emb prefetch for TT+1 while nt1 chain completes */                       \
      const unsigned short* ep = &s_emb[xi_n * EPAD + 8 * g];                     \
      ef0 = *(const bf16x8*)ep;                                                   \
      ef1 = *(const bf16x8*)(ep + 32);                                            \
      int tn = ((TT) + 2 < Lv) ? (TT) + 2 : (Lv - 1);                             \
      xi_n = s_x[tn * ROWS + lm];                                                 \
    }                                                                             \
    float h4v = fast_tanh(a1[0]), h5v = fast_tanh(a1[1]);                         \
    float h6v = fast_tanh(a1[2]), h7v = fast_tanh(a1[3]);                         \
    u32x2 p1;                                                                     \
    p1[0] = cvtpk_bf16(h4v, h5v);                                                 \
    p1[1] = cvtpk_bf16(h6v, h7v);                                                 \
    *(u32x2*)(wa[1] + (WB)) = p1;                                                 \
    *(u32x2*)(hp + 16) = p1; /* hs[TT], nt=1 */                                   \
    hp += TSL;                                                                    \
    if (LAST) {                                                                   \
      float* fo = out + HOFF + (size_t)(r0 + lm) * Hv + 32 * w + 4 * g;           \
      *(f32x4*)fo = (f32x4){h0v, h1v, h2v, h3v};                                  \
      *(f32x4*)(fo + 16) = (f32x4){h4v, h5v, h6v, h7v};                           \
    }                                                                             \
    step_barrier();                                                               \
  } while (0)

  STEPB(0, HB, 0, 0);  // h_{-1}(buf1) -> h_0(buf0), export hs[0]
  for (int t = 1; t < Lv - 1; t += 2) {
    STEPB(t, 0, HB, 0);
    STEPB(t + 1, HB, 0, 0);
  }
  STEPB(Lv - 1, 0, HB, 1);  // hs[1023] + final hidden fp32
#undef STEPB
}

// Deferred logits: out[b][t][v] = hs[t][b][:]@W_ho + b_ho, full chip.
__global__ __launch_bounds__(512, 2) void logits_gemm(
    const unsigned short* __restrict__ hs, const float* __restrict__ W_ho,
    const float* __restrict__ b_ho, float* __restrict__ out) {
  const int tid = threadIdx.x;
  const int w = tid >> 6, ln = tid & 63, lm = ln & 15, g = ln >> 4;
  const int tg = blockIdx.x >> 2, bg = blockIdx.x & 3;

  __shared__ __attribute__((aligned(16))) unsigned short s_who[3072 * 8];
  for (int f = tid; f < 3072; f += 512) {
    int vt = f >> 9, kf = (f >> 6) & 7, lane = f & 63;
    int k0 = 32 * kf + 8 * (lane >> 4), v = 16 * vt + (lane & 15);
    bf16x8 fr;
#pragma unroll
    for (int i = 0; i < 8; ++i) fr[i] = (short)f2b(W_ho[(k0 + i) * Vv + v]);
    *(bf16x8*)&s_who[f * 8] = fr;
  }
  __syncthreads();

  const int bt = w & 3, vg = w >> 2;
  const int b0 = bg * 64 + bt * 16;
  const int j0 = vg * 3;
  float bb[3];
#pragma unroll
  for (int jj = 0; jj < 3; ++jj) bb[jj] = b_ho[16 * (j0 + jj) + lm];

#pragma unroll
  for (int tt = 0; tt < 4; ++tt) {
    const int t = tg * 4 + tt;
    const unsigned short* hpb = hs + (size_t)t * TSL + (b0 + lm) * 256 + 8 * g;
    f32x4 acc[3];
#pragma unroll
    for (int jj = 0; jj < 3; ++jj)
      acc[jj] = (f32x4){bb[jj], bb[jj], bb[jj], bb[jj]};
#pragma unroll
    for (int kf = 0; kf < 8; ++kf) {
      bf16x8 af = *(const bf16x8*)(hpb + 32 * kf);
#pragma unroll
      for (int jj = 0; jj < 3; ++jj) {
        bf16x8 bw = *(const bf16x8*)&s_who[(((j0 + jj) * 8 + kf) * 64 + ln) * 8];
        acc[jj] =
            __builtin_amdgcn_mfma_f32_16x16x32_bf16(af, bw, acc[jj], 0, 0, 0);
      }
    }
#pragma unroll
    for (int jj = 0; jj < 3; ++jj)
#pragma unroll
      for (int rr = 0; rr < 4; ++rr)
        out[(size_t)(b0 + 4 * g + rr) * (Lv * Vv) + (size_t)t * Vv +
            16 * (j0 + jj) + lm] = acc[jj][rr];
  }
}

// ===================== fallback (R2 kernel, ws too small) =====================
__global__ __launch_bounds__(512, 2) void rnn8(
    const int* __restrict__ x, const float* __restrict__ h0,
    const float* __restrict__ emb, const float* __restrict__ W_ih,
    const float* __restrict__ b_ih, const float* __restrict__ W_ho,
    const float* __restrict__ b_ho, float* __restrict__ out,
    const int* __restrict__ flagp) {
  const int tid = threadIdx.x;
  const int w = tid >> 6, ln = tid & 63, lm = ln & 15, g = ln >> 4;
  const int r0 = blockIdx.x * ROWS;

  __shared__ __attribute__((aligned(16))) unsigned short s_emb[Vv * EPAD];
  __shared__ __attribute__((aligned(16))) unsigned short s_h[2 * HB];
  __shared__ unsigned char s_x[Lv * ROWS];

  const int flag = *flagp;

  for (int idx = tid; idx < Vv * Ev; idx += 512)
    s_emb[(idx >> 6) * EPAD + (idx & 63)] = f2b(emb[idx]);
  for (int idx = tid; idx < ROWS * Hv; idx += 512) {
    int m = idx >> 8, nn = idx & 255;
    s_h[HB + (m << 8) + ((((nn >> 3) ^ (m & 7)) << 3) | (nn & 7))] =
        f2b(h0[(r0 + m) * Hv + nn]);
  }
  for (int idx = tid; idx < ROWS * Lv; idx += 512) {
    int row = idx >> 10, t = idx & 1023;
    long long src = (long long)(r0 + row) * Lv + t;
    int v = flag ? x[2 * src] : x[src];
    s_x[t * ROWS + row] = (unsigned char)v;
  }

  bf16x8 wh[2][8], wx[2][2], who[8];
  float bih[2], bhov = 0.0f;
#pragma unroll
  for (int nt = 0; nt < 2; ++nt) {
    const int n = 32 * w + 16 * nt + lm;
    bih[nt] = b_ih[n];
#pragma unroll
    for (int kf = 0; kf < 8; ++kf)
#pragma unroll
      for (int i = 0; i < 8; ++i)
        wh[nt][kf][i] = (short)f2b(W_ih[(Ev + 32 * kf + 8 * g + i) * Hv + n]);
#pragma unroll
    for (int kf = 0; kf < 2; ++kf)
#pragma unroll
      for (int i = 0; i < 8; ++i)
        wx[nt][kf][i] = (short)f2b(W_ih[(32 * kf + 8 * g + i) * Hv + n]);
  }
  if (w < 6) {
    const int n = 16 * w + lm;
    bhov = b_ho[n];
#pragma unroll
    for (int kf = 0; kf < 8; ++kf)
#pragma unroll
      for (int i = 0; i < 8; ++i)
        who[kf][i] = (short)f2b(W_ho[(32 * kf + 8 * g + i) * Vv + n]);
  }

  const unsigned short* ra[8];
#pragma unroll
  for (int kf = 0; kf < 8; ++kf)
    ra[kf] = &s_h[(lm << 8) + (((4 * kf + g) ^ (lm & 7)) << 3)];
  unsigned short* wa[8];
#pragma unroll
  for (int nt = 0; nt < 2; ++nt)
#pragma unroll
    for (int rr = 0; rr < 4; ++rr) {
      int m = 4 * g + rr, n = 32 * w + 16 * nt + lm;
      wa[nt * 4 + rr] = &s_h[(m << 8) + ((((n >> 3) ^ (m & 7)) << 3) | (n & 7))];
    }
  float* ob[4] = {out, out, out, out};
  if (w < 6) {
#pragma unroll
    for (int rr = 0; rr < 4; ++rr)
      ob[rr] = out + (size_t)(r0 + 4 * g + rr) * (Lv * Vv) + 16 * w + lm;
  }

  __syncthreads();

  bf16x8 ef0, ef1;
  {
    int xi = s_x[lm];
    const unsigned short* ep = &s_emb[xi * EPAD + 8 * g];
    ef0 = *(const bf16x8*)ep;
    ef1 = *(const bf16x8*)(ep + 32);
  }

#define STEP8(TT, RB, WB, DOLOG, LAST)                                             \
  do {                                                                             \
    bf16x8 af[8];                                                                  \
    _Pragma("unroll") for (int kf = 0; kf < 8; ++kf)                               \
        af[kf] = *(const bf16x8*)(ra[kf] + (RB));                                  \
    f32x4 a0 = {bih[0], bih[0], bih[0], bih[0]};                                   \
    f32x4 a1 = {bih[1], bih[1], bih[1], bih[1]};                                   \
    a0 = __builtin_amdgcn_mfma_f32_16x16x32_bf16(ef0, wx[0][0], a0, 0, 0, 0);      \
    a1 = __builtin_amdgcn_mfma_f32_16x16x32_bf16(ef0, wx[1][0], a1, 0, 0, 0);      \
    a0 = __builtin_amdgcn_mfma_f32_16x16x32_bf16(ef1, wx[0][1], a0, 0, 0, 0);      \
    a1 = __builtin_amdgcn_mfma_f32_16x16x32_bf16(ef1, wx[1][1], a1, 0, 0, 0);      \
    _Pragma("unroll") for (int kf = 0; kf < 8; ++kf) {                             \
      a0 = __builtin_amdgcn_mfma_f32_16x16x32_bf16(af[kf], wh[0][kf], a0, 0, 0, 0);\
      a1 = __builtin_amdgcn_mfma_f32_16x16x32_bf16(af[kf], wh[1][kf], a1, 0, 0, 0);\
    }                                                                              \
    if ((DOLOG) && w < 6) {                                                        \
      f32x4 l = {bhov, bhov, bhov, bhov};                                          \
      _Pragma("unroll") for (int kf = 0; kf < 8; ++kf)                             \
          l = __builtin_amdgcn_mfma_f32_16x16x32_bf16(af[kf], who[kf], l, 0, 0, 0);\
      const size_t o = (size_t)((TT)-1) * Vv;                                      \
      ob[0][o] = l[0]; ob[1][o] = l[1]; ob[2][o] = l[2]; ob[3][o] = l[3];          \
    }                                                                              \
    {                                                                              \
      int tn = ((TT) + 1 < Lv) ? (TT) + 1 : (Lv - 1);                              \
      int xi = s_x[tn * ROWS + lm];                                                \
      const unsigned short* ep = &s_emb[xi * EPAD + 8 * g];                        \
      ef0 = *(const bf16x8*)ep;                                                    \
      ef1 = *(const bf16x8*)(ep + 32);                                             \
    }                                                                              \
    float th0 = fast_tanh(a0[0]), th1 = fast_tanh(a0[1]);                          \
    float th2 = fast_tanh(a0[2]), th3 = fast_tanh(a0[3]);                          \
    float th4 = fast_tanh(a1[0]), th5 = fast_tanh(a1[1]);                          \
    float th6 = fast_tanh(a1[2]), th7 = fast_tanh(a1[3]);                          \
    unsigned p01 = cvtpk_bf16(th0, th1), p23 = cvtpk_bf16(th2, th3);               \
    unsigned p45 = cvtpk_bf16(th4, th5), p67 = cvtpk_bf16(th6, th7);               \
    wa[0][WB] = (unsigned short)p01;                                               \
    wa[1][WB] = (unsigned short)(p01 >> 16);                                       \
    wa[2][WB] = (unsigned short)p23;                                               \
    wa[3][WB] = (unsigned short)(p23 >> 16);                                       \
    wa[4][WB] = (unsigned short)p45;                                               \
    wa[5][WB] = (unsigned short)(p45 >> 16);                                       \
    wa[6][WB] = (unsigned short)p67;                                               \
    wa[7][WB] = (unsigned short)(p67 >> 16);                                       \
    if (LAST) {                                                                    \
      float* fh = out + HOFF + (size_t)(r0 + 4 * g) * Hv + 32 * w + lm;            \
      fh[0 * Hv] = th0; fh[1 * Hv] = th1; fh[2 * Hv] = th2; fh[3 * Hv] = th3;      \
      fh[0 * Hv + 16] = th4; fh[1 * Hv + 16] = th5;                                \
      fh[2 * Hv + 16] = th6; fh[3 * Hv + 16] = th7;                                \
    }                                                                              \
    asm volatile("s_waitcnt lgkmcnt(0)\n\ts_barrier" ::: "memory");                \
    __builtin_amdgcn_sched_barrier(0);                                             \
  } while (0)

  STEP8(0, HB, 0, 0, 0);
  for (int t = 1; t < Lv - 1; t += 2) {
    STEP8(t, 0, HB, 1, 0);
    STEP8(t + 1, HB, 0, 1, 0);
  }
  STEP8(Lv - 1, 0, HB, 1, 1);

  if (w < 6) {
    bf16x8 af[8];
#pragma unroll
    for (int kf = 0; kf < 8; ++kf) af[kf] = *(const bf16x8*)(ra[kf] + HB);
    f32x4 l = {bhov, bhov, bhov, bhov};
#pragma unroll
    for (int kf = 0; kf < 8; ++kf)
      l = __builtin_amdgcn_mfma_f32_16x16x32_bf16(af[kf], who[kf], l, 0, 0, 0);
    const size_t o = (size_t)(Lv - 1) * Vv;
    ob[0][o] = l[0]; ob[1][o] = l[1]; ob[2][o] = l[2]; ob[3][o] = l[3];
  }
#undef STEP8
}

extern "C" void kernel_launch(void* const* d_in, const int* in_sizes, int n_in,
                              void* d_out, int out_size, void* d_ws, size_t ws_size,
                              hipStream_t stream) {
  const int* x     = (const int*)d_in[0];
  const float* h0  = (const float*)d_in[1];
  const float* emb = (const float*)d_in[2];
  const float* Wih = (const float*)d_in[3];
  const float* bih = (const float*)d_in[4];
  const float* Who = (const float*)d_in[5];
  const float* bho = (const float*)d_in[6];
  float* out = (float*)d_out;
  int* flag = (int*)d_ws;

  const size_t hs_bytes = (size_t)Lv * 256 * 256 * 2;  // 134.2 MB
  detect_i64<<<1, 64, 0, stream>>>(x, flag);
  if (ws_size >= hs_bytes + 256) {
    unsigned short* hs = (unsigned short*)((char*)d_ws + 256);
    rnn8t<<<16, 512, 0, stream>>>(x, h0, emb, Wih, bih, out, hs, flag);
    logits_gemm<<<1024, 512, 0, stream>>>(hs, Who, bho, out);
  } else {
    rnn8<<<16, 512, 0, stream>>>(x, h0, emb, Wih, bih, Who, bho, out, flag);
  }
}